// Round 14
// baseline (3143.623 us; speedup 1.0000x reference)
//
#include <hip/hip_runtime.h>
#include <hip/hip_bf16.h>
#include <math.h>

using f32x4 = __attribute__((ext_vector_type(4))) float;
using s16x8 = __attribute__((ext_vector_type(8))) short;
typedef unsigned short u16;
typedef unsigned int u32;
typedef unsigned long long u64;

#define MFMA16(a,b,c) __builtin_amdgcn_mfma_f32_16x16x32_bf16(a,b,c,0,0,0)
#define SCOPE_A __HIP_MEMORY_SCOPE_AGENT
#define FP 16   // flag padding (ints) = 64B/flag -> parallel stores, no line contention
#define VNS 25

__device__ __forceinline__ float bf2f(u16 u){
  union { u32 i; float f; } v; v.i = ((u32)u) << 16; return v.f;
}
__device__ __forceinline__ u16 f2bf(float f){
  union { float f; u32 i; } v; v.f = f;
  u32 x = v.i;
  return (u16)((x + 0x7fffu + ((x >> 16) & 1u)) >> 16);
}
__device__ __forceinline__ float sigm(float x){ return 1.0f/(1.0f + expf(-x)); }

__device__ __forceinline__ s16x8 pack8(const float* p){
  s16x8 r;
  #pragma unroll
  for (int i = 0; i < 8; ++i) r[i] = (short)f2bf(p[i]);
  return r;
}

// coherent (L3 write-through) store for cross-block data; reads are plain
// cached loads of write-once ring addresses (fresh within the launch).
__device__ __forceinline__ void coh_st32(void* p, u32 v){
  __hip_atomic_store((u32*)p, v, __ATOMIC_RELAXED, SCOPE_A);
}
__device__ __forceinline__ float u2f(u32 u){ union { u32 i; float f; } v; v.i = u; return v.f; }
__device__ __forceinline__ u32 f2u(float f){ union { float f; u32 i; } v; v.f = f; return v.i; }

// flag sync: padded per-block flags (parallel independent stores, one line per
// flag), wave-distributed polls.
__device__ __forceinline__ void poll(const int* flags, int n, int gen){
  for (int i = threadIdx.x; i < n; i += 256)
    while (__hip_atomic_load(flags + i*FP, __ATOMIC_RELAXED, SCOPE_A) < gen)
      __builtin_amdgcn_s_sleep(1);
  __syncthreads();
}
__device__ __forceinline__ void setflag(int* flag, int gen){
  __syncthreads();
  if (threadIdx.x == 0)
    __hip_atomic_store(flag, gen, __ATOMIC_RELAXED, SCOPE_A);
}

// K=1024 GEMM inner: plain cached A loads (16-deep staged) x 2 LDS B cols
__device__ __forceinline__ void gemm_k1024(
    const u16* ap, const char* wb0, const char* wb1, int xo, int addb,
    f32x4& a0, f32x4& a1)
{
  #pragma unroll
  for (int c = 0; c < 2; ++c){
    s16x8 st[16];
    #pragma unroll
    for (int q = 0; q < 16; ++q) st[q] = *(const s16x8*)(ap + c*512 + q*32);
    #pragma unroll
    for (int q = 0; q < 16; ++q){
      int cb = (addb + (c*512 + q*32)*2) ^ xo;
      a0 = MFMA16(st[q], *(const s16x8*)(wb0 + cb), a0);
      a1 = MFMA16(st[q], *(const s16x8*)(wb1 + cb), a1);
    }
  }
}

// vocab LSE tile body: 128 rows x 1280 cols (10 x 128-col subtiles), K=1024.
// As/Bs: [128][72] LDS; mg: [128][2] float2 LDS.
__device__ __forceinline__ void vocab_tile(
    const u16* __restrict__ Cbf, const u16* __restrict__ Wv,
    float2* __restrict__ partials,
    u16 (*As)[72], u16 (*Bs)[72], float2 (*mg)[2],
    int rb, int sp)
{
  const int t = threadIdx.x, w = t >> 6, l = t & 63, lr = l & 15, lh = l >> 4;
  const int wr = w >> 1, wc = w & 1;
  const int sr = t >> 1, sk = (t & 1) << 5;
  const int m0 = rb*128;

  float mrun[4][4], srun[4][4];
  #pragma unroll
  for (int m = 0; m < 4; ++m)
    #pragma unroll
    for (int rr = 0; rr < 4; ++rr){ mrun[m][rr] = -INFINITY; srun[m][rr] = 0.f; }

  for (int nt = 0; nt < 10; ++nt){
    int n0 = sp*1280 + nt*128;
    f32x4 acc[4][4];
    #pragma unroll
    for (int m = 0; m < 4; ++m)
      #pragma unroll
      for (int n = 0; n < 4; ++n) acc[m][n] = (f32x4){0,0,0,0};

    for (int kc = 0; kc < 1024; kc += 64){
      int ar = m0 + sr; if (ar > 3007) ar = 3007;
      const u16* ap = Cbf + (size_t)ar*1024 + kc + sk;
      const u16* wp = Wv + (size_t)(n0 + sr)*1024 + kc + sk;
      #pragma unroll
      for (int q = 0; q < 4; ++q){
        *(s16x8*)&As[sr][sk + q*8] = *(const s16x8*)(ap + q*8);
        *(s16x8*)&Bs[sr][sk + q*8] = *(const s16x8*)(wp + q*8);
      }
      __syncthreads();
      #pragma unroll
      for (int kk = 0; kk < 64; kk += 32){
        s16x8 af[4], bf[4];
        #pragma unroll
        for (int m = 0; m < 4; ++m)
          af[m] = *(const s16x8*)&As[wr*64 + m*16 + lr][kk + lh*8];
        #pragma unroll
        for (int n = 0; n < 4; ++n)
          bf[n] = *(const s16x8*)&Bs[wc*64 + n*16 + lr][kk + lh*8];
        #pragma unroll
        for (int m = 0; m < 4; ++m)
          #pragma unroll
          for (int n = 0; n < 4; ++n)
            acc[m][n] = MFMA16(af[m], bf[n], acc[m][n]);
      }
      __syncthreads();
    }
    #pragma unroll
    for (int m = 0; m < 4; ++m){
      #pragma unroll
      for (int rr = 0; rr < 4; ++rr){
        float tm = fmaxf(fmaxf(acc[m][0][rr], acc[m][1][rr]),
                         fmaxf(acc[m][2][rr], acc[m][3][rr]));
        #pragma unroll
        for (int d = 1; d < 16; d <<= 1) tm = fmaxf(tm, __shfl_xor(tm, d, 64));
        float ts = expf(acc[m][0][rr] - tm) + expf(acc[m][1][rr] - tm)
                 + expf(acc[m][2][rr] - tm) + expf(acc[m][3][rr] - tm);
        #pragma unroll
        for (int d = 1; d < 16; d <<= 1) ts += __shfl_xor(ts, d, 64);
        if (tm > mrun[m][rr]){ srun[m][rr] = srun[m][rr]*expf(mrun[m][rr] - tm) + ts; mrun[m][rr] = tm; }
        else srun[m][rr] += ts*expf(tm - mrun[m][rr]);
      }
    }
  }
  __syncthreads();
  if (lr == 0){
    #pragma unroll
    for (int m = 0; m < 4; ++m)
      #pragma unroll
      for (int rr = 0; rr < 4; ++rr)
        mg[wr*64 + m*16 + lh*4 + rr][wc] = make_float2(mrun[m][rr], srun[m][rr]);
  }
  __syncthreads();
  if (t < 128){
    float2 p0 = mg[t][0], p1 = mg[t][1];
    float m = fmaxf(p0.x, p1.x);
    float s = p0.y*expf(p0.x - m) + p1.y*expf(p1.x - m);
    long row = m0 + t;
    if (row < 3008) partials[row*VNS + sp] = make_float2(m, s);
  }
  __syncthreads();
}

// ---------------- small utility kernels ----------------
__global__ void k_zero(float* __restrict__ p, long n){
  long i = (long)blockIdx.x*blockDim.x + threadIdx.x;
  long st = (long)gridDim.x*blockDim.x;
  for (; i < n; i += st) p[i] = 0.0f;
}

__global__ void k_cast_bf16(const float* __restrict__ src, u16* __restrict__ dst, long n){
  long i = ((long)blockIdx.x*blockDim.x + threadIdx.x)*4;
  long st = (long)gridDim.x*blockDim.x*4;
  for (; i < n; i += st){
    float4 v = *(const float4*)(src + i);
    *(ushort4*)(dst + i) = make_ushort4(f2bf(v.x), f2bf(v.y), f2bf(v.z), f2bf(v.w));
  }
}

__global__ void k_addv(const float* __restrict__ a, const float* __restrict__ b,
                       float* __restrict__ d, int n){
  int i = blockIdx.x*blockDim.x + threadIdx.x;
  if (i < n) d[i] = a[i] + b[i];
}

// cnn_w (512,512,2) -> Wconv_bf [512][1024] = [W0 | W1]
__global__ void k_repack_conv(const float* __restrict__ w, u16* __restrict__ dst){
  int i = blockIdx.x*256 + threadIdx.x;
  int o = i >> 9, ii = i & 511;
  dst[(size_t)o*1024 + ii]       = f2bf(w[((size_t)o*512 + ii)*2 + 0]);
  dst[(size_t)o*1024 + 512 + ii] = f2bf(w[((size_t)o*512 + ii)*2 + 1]);
}

// Wy[4096][512] = dec_Wih[:, 1024:1536]
__global__ void k_build_wy(const float* __restrict__ dWih, u16* __restrict__ Wy){
  int i = blockIdx.x*256 + threadIdx.x;
  int r = i >> 9, c = i & 511;
  Wy[(size_t)r*512 + c] = f2bf(dWih[(size_t)r*1536 + 1024 + c]);
}

// Wcomb (1024,3072) -> Wca [1024][2048], Whp [1024][1024]
__global__ void k_split_wcomb(const float* __restrict__ Wcomb,
                              u16* __restrict__ Wca, u16* __restrict__ Whp){
  int r = blockIdx.x;
  for (int c = threadIdx.x; c < 2048; c += 256)
    Wca[(size_t)r*2048 + c] = f2bf(Wcomb[(size_t)r*3072 + c]);
  for (int c = threadIdx.x; c < 1024; c += 256)
    Whp[(size_t)r*1024 + c] = f2bf(Wcomb[(size_t)r*3072 + 2048 + c]);
}

__global__ void k_gather_src(const int* __restrict__ ids, const float* __restrict__ emb,
                             u16* __restrict__ Aconv){
  int s = blockIdx.x;
  int b = blockIdx.y;
  int e = threadIdx.x*4;
  float4 v = make_float4(0.f,0.f,0.f,0.f);
  if (s < 48){ int id = ids[s*64 + b]; v = *(const float4*)(emb + (size_t)id*512 + e); }
  ushort4 u = make_ushort4(f2bf(v.x), f2bf(v.y), f2bf(v.z), f2bf(v.w));
  if (s < 48) *(ushort4*)(Aconv + ((size_t)(s*64 + b))*1024 + e) = u;
  if (s >= 1) *(ushort4*)(Aconv + ((size_t)((s-1)*64 + b))*1024 + 512 + e) = u;
}

__global__ void k_gather_y(const int* __restrict__ ids, const float* __restrict__ emb,
                           u16* __restrict__ Y){
  int t = blockIdx.x; int b = blockIdx.y; int e = threadIdx.x*4;
  int id = ids[t*64 + b];
  float4 v = *(const float4*)(emb + (size_t)id*512 + e);
  *(ushort4*)(Y + ((size_t)(t*64 + b))*512 + e) = make_ushort4(f2bf(v.x), f2bf(v.y), f2bf(v.z), f2bf(v.w));
}

// ---------------- universal MFMA GEMM (prologue use) ----------------
// PACKG: gate-packed GP[time][j(1024)][gate(4)][b(64)] bf16
template<bool OUT_BF16, bool PACKG>
__global__ __launch_bounds__(256) void k_gemm(
    const u16* __restrict__ A0, long lda0,
    const u16* __restrict__ A1, long lda1, int ksplit,
    const u16* __restrict__ W, int K,
    void* __restrict__ Out, long ldc,
    const float* __restrict__ bias)
{
  __shared__ __align__(16) u16 As[64][72];
  __shared__ __align__(16) u16 Ws[64][72];
  const int t = threadIdx.x;
  const int m0 = blockIdx.x*64, n0 = blockIdx.y*64;
  const int w = t >> 6, l = t & 63, lr = l & 15, lh = l >> 4;
  const int sr = t >> 2, sk = (t & 3) << 4;

  f32x4 acc[4] = {{0,0,0,0},{0,0,0,0},{0,0,0,0},{0,0,0,0}};

  for (int kc = 0; kc < K; kc += 64){
    {
      const u16* wp = W + (size_t)(n0 + sr)*K + kc + sk;
      *(s16x8*)&Ws[sr][sk]     = *(const s16x8*)wp;
      *(s16x8*)&Ws[sr][sk + 8] = *(const s16x8*)(wp + 8);
    }
    {
      const u16* ap = (kc < ksplit)
        ? A0 + (size_t)(m0 + sr)*lda0 + kc
        : A1 + (size_t)(m0 + sr)*lda1 + (kc - ksplit);
      ap += sk;
      *(s16x8*)&As[sr][sk]     = *(const s16x8*)ap;
      *(s16x8*)&As[sr][sk + 8] = *(const s16x8*)(ap + 8);
    }
    __syncthreads();
    #pragma unroll
    for (int kk = 0; kk < 64; kk += 32){
      s16x8 a = *(const s16x8*)&As[w*16 + lr][kk + lh*8];
      #pragma unroll
      for (int ct = 0; ct < 4; ++ct){
        s16x8 bfr = *(const s16x8*)&Ws[ct*16 + lr][kk + lh*8];
        acc[ct] = MFMA16(a, bfr, acc[ct]);
      }
    }
    __syncthreads();
  }
  #pragma unroll
  for (int ct = 0; ct < 4; ++ct){
    #pragma unroll
    for (int rr = 0; rr < 4; ++rr){
      long row = m0 + w*16 + lh*4 + rr;
      long col = n0 + ct*16 + lr;
      float v = acc[ct][rr];
      if (bias) v += bias[col];
      if (PACKG){
        long time = row >> 6, b = row & 63, g = col >> 10, j = col & 1023;
        ((u16*)Out)[((time*1024 + j)*4 + g)*64 + b] = f2bf(v);
      } else {
        long oi = row*ldc + col;
        if (OUT_BF16) ((u16*)Out)[oi] = f2bf(v);
        else          ((float*)Out)[oi] = v;
      }
    }
  }
}

// ---------------- persistent encoder + fused helpers ----------------
__global__ __launch_bounds__(256) void k_enc_persist(
    const float* __restrict__ WhhF, const float* __restrict__ WhhB,
    const u16* __restrict__ GfP, const u16* __restrict__ GbP,
    u16* __restrict__ hEF, u16* __restrict__ hEB,
    const u16* __restrict__ hzero,
    float* __restrict__ cF, float* __restrict__ cB,
    u16* __restrict__ Aatt, u16* __restrict__ cfbf, u16* __restrict__ cbbf,
    int* Eflags,
    const u16* __restrict__ Ybf, const u16* __restrict__ WyBf,
    const float* __restrict__ bdec, u16* __restrict__ GyP,
    const float* __restrict__ Wv, u16* __restrict__ WvBf)
{
  extern __shared__ char smem[];
  const int t = threadIdx.x, blk = blockIdx.x;
  const int w = t >> 6, l = t & 63, lr = l & 15, lh = l >> 4;

  if (blk >= 128){
    // ================= helpers =================
    const int hb = blk - 128;
    u16 (*As)[72] = (u16(*)[72])smem;
    u16 (*Ws)[72] = (u16(*)[72])(smem + 64*72*2);
    const int sr = t >> 2, sk = (t & 3) << 4;
    for (int tile = hb; tile < 47*64; tile += 128){
      int m0 = (tile % 47)*64, n0 = (tile / 47)*64;
      f32x4 acc[4] = {{0,0,0,0},{0,0,0,0},{0,0,0,0},{0,0,0,0}};
      for (int kc = 0; kc < 512; kc += 64){
        const u16* wp = WyBf + (size_t)(n0 + sr)*512 + kc + sk;
        *(s16x8*)&Ws[sr][sk]     = *(const s16x8*)wp;
        *(s16x8*)&Ws[sr][sk + 8] = *(const s16x8*)(wp + 8);
        const u16* ap = Ybf + (size_t)(m0 + sr)*512 + kc + sk;
        *(s16x8*)&As[sr][sk]     = *(const s16x8*)ap;
        *(s16x8*)&As[sr][sk + 8] = *(const s16x8*)(ap + 8);
        __syncthreads();
        #pragma unroll
        for (int kk = 0; kk < 64; kk += 32){
          s16x8 a = *(const s16x8*)&As[w*16 + lr][kk + lh*8];
          #pragma unroll
          for (int ct = 0; ct < 4; ++ct){
            s16x8 bfr = *(const s16x8*)&Ws[ct*16 + lr][kk + lh*8];
            acc[ct] = MFMA16(a, bfr, acc[ct]);
          }
        }
        __syncthreads();
      }
      #pragma unroll
      for (int ct = 0; ct < 4; ++ct){
        #pragma unroll
        for (int rr = 0; rr < 4; ++rr){
          long row = m0 + w*16 + lh*4 + rr;
          long col = n0 + ct*16 + lr;
          float v = acc[ct][rr] + bdec[col];
          long time = row >> 6, b = row & 63, g = col >> 10, j = col & 1023;
          GyP[((time*1024 + j)*4 + g)*64 + b] = f2bf(v);
        }
      }
    }
    for (long i = ((long)hb*256 + t)*4; i < (long)32000*1024; i += (long)128*256*4){
      float4 v = *(const float4*)(Wv + i);
      *(ushort4*)(WvBf + i) = make_ushort4(f2bf(v.x), f2bf(v.y), f2bf(v.z), f2bf(v.w));
    }
    return;
  }

  // ================= encoder =================
  const int dir = blk >> 6;
  const int j0 = (blk & 63) << 4;
  const float* Wsrc = dir ? WhhB : WhhF;
  const u16* GP = dir ? GbP : GfP;
  float* c = dir ? cB : cF;
  u16* cobf = dir ? cbbf : cfbf;
  u16* hE = dir ? hEB : hEF;
  int* myflags = Eflags + dir*64*FP;
  const int myidx = blk & 63;

  for (int q = t; q < 64*128; q += 256){
    int row = q >> 7;
    int ck = (q & 127) << 3;
    int wrow = ((row >> 4)*1024) + j0 + (row & 15);
    s16x8 pk = pack8(Wsrc + (size_t)wrow*1024 + ck);
    *(s16x8*)(smem + row*2048 + ((ck*2) ^ ((row & 7) << 4))) = pk;
  }
  __syncthreads();

  const int lane_m = w*16 + lr;
  const int koff = lh*8;
  const char* wp0 = smem + lr*2048;
  const char* wp1 = smem + (16 + lr)*2048;
  const char* wp2 = smem + (32 + lr)*2048;
  const char* wp3 = smem + (48 + lr)*2048;
  const int xo = (lr & 7) << 4;
  const int j = j0 + lr;

  for (int s = 0; s < 48; ++s){
    const u16* hin = s ? (hE + (size_t)(s - 1)*65536) : hzero;
    u16* hout      = hE + (size_t)s*65536;
    const int time = dir ? 47 - s : s;
    if (s) poll(myflags, 64, s);
    f32x4 a0 = {0,0,0,0}, a1 = {0,0,0,0}, a2 = {0,0,0,0}, a3 = {0,0,0,0};
    const u16* ap = hin + (size_t)lane_m*1024 + koff;
    #pragma unroll
    for (int cc = 0; cc < 2; ++cc){
      s16x8 st[16];
      #pragma unroll
      for (int q = 0; q < 16; ++q) st[q] = *(const s16x8*)(ap + cc*512 + q*32);
      #pragma unroll
      for (int q = 0; q < 16; ++q){
        int cb = ((cc*512 + q*32 + koff)*2) ^ xo;
        a0 = MFMA16(st[q], *(const s16x8*)(wp0 + cb), a0);
        a1 = MFMA16(st[q], *(const s16x8*)(wp1 + cb), a1);
        a2 = MFMA16(st[q], *(const s16x8*)(wp2 + cb), a2);
        a3 = MFMA16(st[q], *(const s16x8*)(wp3 + cb), a3);
      }
    }
    #pragma unroll
    for (int rr = 0; rr < 4; ++rr){
      int b = w*16 + lh*4 + rr;
      const u16* gp = GP + (((size_t)time*1024 + j)*4)*64 + b;
      float gi = a0[rr] + bf2f(gp[0]);
      float gf = a1[rr] + bf2f(gp[64]);
      float gg = a2[rr] + bf2f(gp[128]);
      float go = a3[rr] + bf2f(gp[192]);
      float cn = sigm(gf)*c[b*1024 + j] + sigm(gi)*tanhf(gg);
      float hn = sigm(go)*tanhf(cn);
      c[b*1024 + j] = cn;
      u16 hb = f2bf(hn);
      u32 hi2 = __shfl_down((u32)hb, 1);
      if ((lr & 1) == 0)
        coh_st32((u32*)hout + ((b*1024 + j) >> 1), (u32)hb | (hi2 << 16));
      Aatt[((size_t)b*48 + time)*2048 + dir*1024 + j] = hb;
      if (s == 47) cobf[b*1024 + j] = f2bf(cn);
    }
    setflag(myflags + myidx*FP, s + 1);
  }
}

// ---------------- persistent decoder + vocab helpers ----------------
// 256 blocks: G = 0..127 (Wdec 128KB + Whp-slice 16KB; gates + LSTM + hpart),
// SC = 128..191 (batch row each; encP[b] 96KB; scores+softmax+PV+combine),
// V = 192..255 (vocab LSE tiles 0..319 consumed as Cbf rings publish).
__global__ __launch_bounds__(256) void k_dec_persist(
    const float* __restrict__ dWih, const float* __restrict__ dWhh,
    const u16* __restrict__ GyP,
    const u16* __restrict__ encP, const u16* __restrict__ encWc,
    const u16* __restrict__ Whp,
    const u16* __restrict__ hbinit, u16* __restrict__ hD,
    float* __restrict__ cdec,
    u16* __restrict__ hp, u16* __restrict__ Cbf,
    const u16* __restrict__ obf_zero,
    int* Gflags, int* G2flags, int* Cflags,
    const u16* __restrict__ WvBf, float2* __restrict__ partials)
{
  extern __shared__ char smem[];
  const int t = threadIdx.x, blk = blockIdx.x;
  const int w = t >> 6, l = t & 63, lr = l & 15, lh = l >> 4;
  const int lane_m = w*16 + lr;
  const int koff = lh*8;
  const int xo = (lr & 7) << 4;

  if (blk < 128){
    // ================= G: gates GEMM + LSTM + hpart =================
    const int j0 = blk << 3;
    for (int q = t; q < 32*256; q += 256){
      int row = q >> 8;
      int ck = (q & 255) << 3;
      int wrow = ((row >> 3)*1024) + j0 + (row & 7);
      const float* src = (ck < 1024) ? dWih + (size_t)wrow*1536 + ck
                                     : dWhh + (size_t)wrow*1024 + (ck - 1024);
      s16x8 pk = pack8(src);
      *(s16x8*)(smem + row*4096 + ((ck*2) ^ ((row & 7) << 4))) = pk;
    }
    char* WhpL = smem + 131072;   // 8 rows x 1024 bf16 swizzled (16KB)
    for (int q = t; q < 8*128; q += 256){
      int row = q >> 7, ck = (q & 127) << 3;
      s16x8 v = *(const s16x8*)(Whp + (size_t)(j0 + row)*1024 + ck);
      *(s16x8*)(WhpL + row*2048 + ((ck*2) ^ ((row & 7) << 4))) = v;
    }
    __syncthreads();
    const char* wp0 = smem + lr*4096;
    const char* wp1 = smem + (16 + lr)*4096;
    const char* wph = WhpL + (lr & 7)*2048;
    const int jj = lr & 7, gsel = lr >> 3;
    const int j = j0 + jj;

    s16x8 hreg[32];
    {
      const u16* ap = hbinit + (size_t)lane_m*1024 + koff;
      #pragma unroll
      for (int q = 0; q < 32; ++q) hreg[q] = *(const s16x8*)(ap + q*32);
    }

    for (int tt = 0; tt < 47; ++tt){
      u16* hout = hD + (size_t)tt*65536;
      f32x4 a0 = {0,0,0,0}, a1 = {0,0,0,0};
      #pragma unroll
      for (int q = 0; q < 32; ++q){
        int cb = ((1024 + q*32 + koff)*2) ^ xo;
        a0 = MFMA16(hreg[q], *(const s16x8*)(wp0 + cb), a0);
        a1 = MFMA16(hreg[q], *(const s16x8*)(wp1 + cb), a1);
      }
      if (tt) poll(Cflags, 64, tt);           // Cbf[tt-1] ready
      const u16* Ao = tt ? (Cbf + (size_t)(tt - 1)*65536) : obf_zero;
      gemm_k1024(Ao + (size_t)lane_m*1024 + koff, wp0, wp1, xo, koff*2, a0, a1);
      #pragma unroll
      for (int rr = 0; rr < 4; ++rr){
        float v0 = a0[rr], v1 = a1[rr];
        float p0 = __shfl_xor(v0, 8, 64);
        float p1 = __shfl_xor(v1, 8, 64);
        if (gsel == 0){
          int b = w*16 + lh*4 + rr;
          const u16* gp = GyP + (((size_t)tt*1024 + j)*4)*64 + b;
          float gi = v0 + bf2f(gp[0]);
          float gf = p0 + bf2f(gp[64]);
          float gg = v1 + bf2f(gp[128]);
          float go = p1 + bf2f(gp[192]);
          float cn = sigm(gf)*cdec[b*1024 + j] + sigm(gi)*tanhf(gg);
          float hn = sigm(go)*tanhf(cn);
          cdec[b*1024 + j] = cn;
          u16 hb = f2bf(hn);
          u32 hi2 = __shfl_down((u32)hb, 1);
          if ((jj & 1) == 0)
            coh_st32((u32*)hout + ((b*1024 + j) >> 1), (u32)hb | (hi2 << 16));
        }
      }
      setflag(Gflags + blk*FP, tt + 1);
      poll(Gflags, 128, tt + 1);              // full h[tt] ready (peers)
      {
        const u16* ap = hout + (size_t)lane_m*1024 + koff;
        #pragma unroll
        for (int q = 0; q < 32; ++q) hreg[q] = *(const s16x8*)(ap + q*32);
      }
      // hpart (bf16) for own 8 cols: h[tt] @ Whp_slice^T
      f32x4 hpacc = {0,0,0,0};
      #pragma unroll
      for (int q = 0; q < 32; ++q){
        int cb = ((q*32 + koff)*2) ^ xo;
        s16x8 bw = {0,0,0,0,0,0,0,0};
        if (lr < 8) bw = *(const s16x8*)(wph + cb);
        hpacc = MFMA16(hreg[q], bw, hpacc);
      }
      if (lr < 8){
        u16* hpout = hp + (size_t)tt*65536;
        #pragma unroll
        for (int rr = 0; rr < 4; ++rr){
          u16 hb = f2bf(hpacc[rr]);
          u32 hi2 = __shfl_down((u32)hb, 1);
          if ((lr & 1) == 0)
            coh_st32((u32*)hpout + (((size_t)(w*16 + lh*4 + rr)*1024 + j0 + lr) >> 1),
                     (u32)hb | (hi2 << 16));
        }
      }
      setflag(G2flags + blk*FP, tt + 1);
    }
  } else if (blk < 192){
    // ================= SC: scores + softmax + PV + combine (batch b) =========
    const int b = blk - 128;
    u16* encPL = (u16*)smem;              // [48][1024] bf16
    float* hs  = (float*)(smem + 98304);  // [1024]
    float* es  = (float*)(smem + 102400); // [48]
    float* al  = es + 48;                 // [48]
    for (int q = t; q < 48*128; q += 256){
      int row = q >> 7, ck = (q & 127) << 3;
      *(s16x8*)&encPL[row*1024 + ck] =
        *(const s16x8*)(encP + ((size_t)b*48 + row)*1024 + ck);
    }
    __syncthreads();

    for (int tt = 0; tt < 47; ++tt){
      poll(Gflags, 128, tt + 1);           // h[tt] ready
      const u16* hrow = hD + (size_t)tt*65536 + (size_t)b*1024;
      {
        ushort4 v4 = ((const ushort4*)hrow)[t];
        hs[4*t]     = bf2f(v4.x);
        hs[4*t + 1] = bf2f(v4.y);
        hs[4*t + 2] = bf2f(v4.z);
        hs[4*t + 3] = bf2f(v4.w);
      }
      __syncthreads();
      for (int s2 = w; s2 < 48; s2 += 4){
        float p = 0.f;
        #pragma unroll
        for (int i = 0; i < 16; ++i)
          p += hs[l + 64*i]*bf2f(encPL[s2*1024 + l + 64*i]);
        #pragma unroll
        for (int d = 32; d >= 1; d >>= 1) p += __shfl_xor(p, d, 64);
        if (l == 0) es[s2] = p;
      }
      __syncthreads();
      if (w == 0){
        float e = (l < 48) ? es[l] : -INFINITY;
        float m = e;
        #pragma unroll
        for (int d = 32; d >= 1; d >>= 1) m = fmaxf(m, __shfl_xor(m, d, 64));
        float ex = (l < 48) ? expf(e - m) : 0.f;
        float su = ex;
        #pragma unroll
        for (int d = 32; d >= 1; d >>= 1) su += __shfl_xor(su, d, 64);
        if (l < 48) al[l] = ex/su;
      }
      __syncthreads();
      poll(G2flags, 128, tt + 1);          // hpart[tt] ready
      int c0 = t*4;
      ushort4 h4 = *(const ushort4*)(hp + (size_t)tt*65536 + (size_t)b*1024 + c0);
      float acc0 = 0.f, acc1 = 0.f, acc2 = 0.f, acc3 = 0.f;
      const u16* ew = encWc + (size_t)b*48*1024 + c0;
      #pragma unroll 4
      for (int s2 = 0; s2 < 48; ++s2){
        float wgt = al[s2];
        ushort4 e4 = *(const ushort4*)(ew + (size_t)s2*1024);
        acc0 += wgt*bf2f(e4.x); acc1 += wgt*bf2f(e4.y);
        acc2 += wgt*bf2f(e4.z); acc3 += wgt*bf2f(e4.w);
      }
      float v0 = tanhf(bf2f(h4.x) + acc0), v1 = tanhf(bf2f(h4.y) + acc1);
      float v2 = tanhf(bf2f(h4.z) + acc2), v3 = tanhf(bf2f(h4.w) + acc3);
      size_t oi = (size_t)tt*65536 + (size_t)b*1024 + c0;
      coh_st32((u32*)Cbf + (oi >> 1),     (u32)f2bf(v0) | ((u32)f2bf(v1) << 16));
      coh_st32((u32*)Cbf + (oi >> 1) + 1, (u32)f2bf(v2) | ((u32)f2bf(v3) << 16));
      setflag(Cflags + b*FP, tt + 1);
    }
  } else {
    // ================= V: vocab LSE tiles 0..319 (5 per block) =================
    const int v = blk - 192;
    u16 (*As)[72] = (u16(*)[72])smem;
    u16 (*Bs)[72] = (u16(*)[72])(smem + 128*72*2);
    float2 (*mg)[2] = (float2(*)[2])(smem + 2*128*72*2);
    for (int tile = v*5; tile < v*5 + 5; ++tile){
      int rb = tile/25, sp = tile - rb*25;
      poll(Cflags, 64, 2*rb + 2);          // Cbf rows for timesteps 2rb,2rb+1
      vocab_tile(Cbf, WvBf, partials, As, Bs, mg, rb, sp);
    }
  }
}

// ---------------- tail vocab GEMM + online logsumexp (tiles >= tile0) --------
__global__ __launch_bounds__(256) void k_vocab_lse(
    const u16* __restrict__ Cbf, const u16* __restrict__ Wv,
    float2* __restrict__ partials, int tile0)
{
  __shared__ __align__(16) u16 As[128][72];
  __shared__ __align__(16) u16 Bs[128][72];
  __shared__ float2 mg[128][2];
  int tile = tile0 + blockIdx.x;
  int rb = tile/25, sp = tile - rb*25;
  vocab_tile(Cbf, Wv, partials, As, Bs, mg, rb, sp);
}

__global__ void k_lse(const float2* __restrict__ partials, float* __restrict__ lse){
  int r = blockIdx.x*256 + threadIdx.x;
  if (r >= 3008) return;
  float m = -INFINITY, s = 0.f;
  for (int i = 0; i < VNS; ++i){
    float2 p = partials[r*VNS + i];
    if (p.x > m){ s = s*expf(m - p.x) + p.y; m = p.x; }
    else s += p.y*expf(p.x - m);
  }
  lse[r] = m + logf(s);
}

__global__ __launch_bounds__(256) void k_gold(const u16* __restrict__ Cbf,
                                              const u16* __restrict__ Wv,
                                              const int* __restrict__ tgt,
                                              float* __restrict__ gold){
  int w = threadIdx.x >> 6, l = threadIdx.x & 63;
  int r = blockIdx.x*4 + w;
  int tt = r >> 6, b = r & 63;
  int gid = tgt[(tt + 1)*64 + b];
  const u16* cp = Cbf + (size_t)r*1024;
  const u16* wp = Wv + (size_t)gid*1024;
  float p = 0.f;
  for (int i = l; i < 1024; i += 64) p += bf2f(cp[i])*bf2f(wp[i]);
  for (int d = 32; d >= 1; d >>= 1) p += __shfl_xor(p, d, 64);
  if (l == 0) gold[r] = p;
}

__global__ void k_final(const float* __restrict__ gold, const float* __restrict__ lse,
                        const int* __restrict__ tgt, float* __restrict__ out){
  int b = threadIdx.x;
  if (b >= 64) return;
  float acc = 0.f;
  for (int t = 0; t < 47; ++t){
    int gid = tgt[(t + 1)*64 + b];
    if (gid != 0) acc += gold[t*64 + b] - lse[t*64 + b];
  }
  out[b] = acc;
}

// ---------------- host ----------------
extern "C" void kernel_launch(void* const* d_in, const int* in_sizes, int n_in,
                              void* d_out, int out_size, void* d_ws, size_t ws_size,
                              hipStream_t stream)
{
  (void)in_sizes; (void)n_in; (void)out_size; (void)ws_size;
  const int*   src_ids = (const int*)d_in[0];
  const int*   tgt_ids = (const int*)d_in[1];
  const float* src_emb = (const float*)d_in[3];
  const float* tgt_emb = (const float*)d_in[4];
  const float* cnn_w   = (const float*)d_in[5];
  const float* cnn_b   = (const float*)d_in[6];
  const float* eWih_f  = (const float*)d_in[7];
  const float* eWhh_f  = (const float*)d_in[8];
  const float* ebih_f  = (const float*)d_in[9];
  const float* ebhh_f  = (const float*)d_in[10];
  const float* eWih_b  = (const float*)d_in[11];
  const float* eWhh_b  = (const float*)d_in[12];
  const float* ebih_b  = (const float*)d_in[13];
  const float* ebhh_b  = (const float*)d_in[14];
  const float* dWih    = (const float*)d_in[15];
  const float* dWhh    = (const float*)d_in[16];
  const float* dbih    = (const float*)d_in[17];
  const float* dbhh    = (const float*)d_in[18];
  const float* Wh      = (const float*)d_in[19];
  const float* Wc      = (const float*)d_in[20];
  const float* Watt    = (const float*)d_in[21];
  const float* Wcomb   = (const float*)d_in[22];
  const float* Wvocab  = (const float*)d_in[23];

  char* ws = (char*)d_ws;
  size_t off = 0;
  auto alloc = [&](size_t bytes)->char*{
    char* p = ws + off;
    off = (off + bytes + 255) & ~(size_t)255;
    return p;
  };

  // --- zero region (contiguous, re-zeroed every launch) ---
  float* cF     = (float*)alloc((size_t)65536*4);
  float* cB     = (float*)alloc((size_t)65536*4);
  u16* obf_zero = (u16*)alloc((size_t)65536*2);
  int* bar      = (int*)alloc(32768);
  size_t zero_floats = ((size_t)262144*2 + 131072 + 32768)/4;
  int* Eflags  = bar;            // 128*FP ints
  int* Gflags  = bar + 2048;     // 128*FP
  int* G2flags = bar + 4096;     // 128*FP
  int* Cflags  = bar + 6144;     // 64*FP

  // --- weights (bf16) ---
  u16* Wconv_bf = (u16*)alloc((size_t)512*1024*2);
  u16* Wih_f_bf = (u16*)alloc((size_t)4096*512*2);
  u16* Wih_b_bf = (u16*)alloc((size_t)4096*512*2);
  u16* Wy_bf    = (u16*)alloc((size_t)4096*512*2);
  u16* Wh_bf    = (u16*)alloc((size_t)1024*2048*2);
  u16* Wc_bf    = (u16*)alloc((size_t)1024*2048*2);
  u16* Watt_bf  = (u16*)alloc((size_t)1024*2048*2);
  u16* Wca_bf   = (u16*)alloc((size_t)1024*2048*2);
  u16* Whp_bf   = (u16*)alloc((size_t)1024*1024*2);
  u16* Wv_bf    = (u16*)alloc((size_t)32000*1024*2);
  float* benc_f = (float*)alloc(4096*4);
  float* benc_b = (float*)alloc(4096*4);
  float* bdec   = (float*)alloc(4096*4);

  // --- activations ---
  u16* Aconv    = (u16*)alloc((size_t)3072*1024*2);
  u16* Xc       = (u16*)alloc((size_t)3072*512*2);
  u16* GfP      = (u16*)alloc((size_t)48*1024*256*2);
  u16* GbP      = (u16*)alloc((size_t)48*1024*256*2);
  u16* GyP      = (u16*)alloc((size_t)47*1024*256*2);
  u16* Ybf      = (u16*)alloc((size_t)3008*512*2);
  u16* Aatt     = (u16*)alloc((size_t)3072*2048*2);
  u16* encP     = (u16*)alloc((size_t)3072*1024*2);
  u16* encWc    = (u16*)alloc((size_t)3072*1024*2);
  u16* hEF      = (u16*)alloc((size_t)48*65536*2);
  u16* hEB      = (u16*)alloc((size_t)48*65536*2);
  u16* cfbf     = (u16*)alloc((size_t)65536*2);
  u16* cbbf     = (u16*)alloc((size_t)65536*2);
  u16* hbinit   = (u16*)alloc((size_t)65536*2);
  u16* hD       = (u16*)alloc((size_t)47*65536*2);
  float* cdec   = (float*)alloc((size_t)65536*4);
  u16* hp       = (u16*)alloc((size_t)47*65536*2);      // hpart ring (bf16)
  u16* Cbf      = (u16*)alloc((size_t)3008*1024*2);
  float2* partials=(float2*)alloc((size_t)3008*VNS*8);
  float* lse    = (float*)alloc(3008*4);
  float* gold   = (float*)alloc(3008*4);

  k_zero<<<256, 256, 0, stream>>>(cF, (long)zero_floats);

  auto cgrid = [](long n)->int{ long g = (n/4 + 255)/256; return (int)(g > 1024 ? 1024 : g); };
  k_cast_bf16<<<cgrid(4096*512), 256, 0, stream>>>(eWih_f, Wih_f_bf, (long)4096*512);
  k_cast_bf16<<<cgrid(4096*512), 256, 0, stream>>>(eWih_b, Wih_b_bf, (long)4096*512);
  k_cast_bf16<<<cgrid(1024*2048), 256, 0, stream>>>(Wh, Wh_bf, (long)1024*2048);
  k_cast_bf16<<<cgrid(1024*2048), 256, 0, stream>>>(Wc, Wc_bf, (long)1024*2048);
  k_cast_bf16<<<cgrid(1024*2048), 256, 0, stream>>>(Watt, Watt_bf, (long)1024*2048);

  k_addv<<<16, 256, 0, stream>>>(ebih_f, ebhh_f, benc_f, 4096);
  k_addv<<<16, 256, 0, stream>>>(ebih_b, ebhh_b, benc_b, 4096);
  k_addv<<<16, 256, 0, stream>>>(dbih, dbhh, bdec, 4096);

  k_repack_conv<<<1024, 256, 0, stream>>>(cnn_w, Wconv_bf);
  k_build_wy<<<8192, 256, 0, stream>>>(dWih, Wy_bf);
  k_split_wcomb<<<1024, 256, 0, stream>>>(Wcomb, Wca_bf, Whp_bf);

  k_gather_src<<<dim3(49, 64), 128, 0, stream>>>(src_ids, src_emb, Aconv);
  k_gather_y<<<dim3(47, 64), 128, 0, stream>>>(tgt_ids, tgt_emb, Ybf);

  // conv + encoder input-gate precomputes (gate-packed outputs)
  k_gemm<true, false><<<dim3(48, 8), 256, 0, stream>>>(
      Aconv, 1024, Aconv, 1024, 1024, Wconv_bf, 1024, Xc, 512, cnn_b);
  k_gemm<true, true><<<dim3(48, 64), 256, 0, stream>>>(
      Xc, 512, Xc, 512, 512, Wih_f_bf, 512, GfP, 0, benc_f);
  k_gemm<true, true><<<dim3(48, 64), 256, 0, stream>>>(
      Xc, 512, Xc, 512, 512, Wih_b_bf, 512, GbP, 0, benc_b);

  // persistent bidirectional encoder + fused helpers
  k_enc_persist<<<256, 256, 131072, stream>>>(
      eWhh_f, eWhh_b, GfP, GbP, hEF, hEB, obf_zero, cF, cB,
      Aatt, cfbf, cbbf, Eflags,
      Ybf, Wy_bf, bdec, GyP, Wvocab, Wv_bf);

  // decoder init: dec_h (bf16), dec_c
  k_gemm<true, false><<<dim3(1, 16), 256, 0, stream>>>(
      hEF + (size_t)47*65536, 1024, hEB + (size_t)47*65536, 1024, 1024,
      Wh_bf, 2048, hbinit, 1024, nullptr);
  k_gemm<false, false><<<dim3(1, 16), 256, 0, stream>>>(
      cfbf, 1024, cbbf, 1024, 1024, Wc_bf, 2048, cdec, 1024, nullptr);
  // encP = enc_hiddens @ Watt^T, encWc = enc_hiddens @ Wcomb_a^T
  k_gemm<true, false><<<dim3(48, 16), 256, 0, stream>>>(
      Aatt, 2048, Aatt, 2048, 2048, Watt_bf, 2048, encP, 1024, nullptr);
  k_gemm<true, false><<<dim3(48, 16), 256, 0, stream>>>(
      Aatt, 2048, Aatt, 2048, 2048, Wca_bf, 2048, encWc, 1024, nullptr);

  // persistent decoder (G + SC + V vocab overlap)
  k_dec_persist<<<256, 256, 147456, stream>>>(
      dWih, dWhh, GyP, encP, encWc, Whp_bf, hbinit, hD, cdec,
      hp, Cbf, obf_zero, Gflags, G2flags, Cflags, Wv_bf, partials);

  // tail vocab (tiles 320..599) + lse + gold + final
  k_vocab_lse<<<280, 256, 0, stream>>>(Cbf, Wv_bf, partials, 320);
  k_lse<<<12, 256, 0, stream>>>(partials, lse);
  k_gold<<<752, 256, 0, stream>>>(Cbf, Wv_bf, tgt_ids, gold);
  k_final<<<1, 64, 0, stream>>>(gold, lse, tgt_ids, (float*)d_out);
}

// Round 15
// 2338.753 us; speedup vs baseline: 1.3441x; 1.3441x over previous
//
#include <hip/hip_runtime.h>
#include <hip/hip_bf16.h>
#include <math.h>

using f32x4 = __attribute__((ext_vector_type(4))) float;
using s16x8 = __attribute__((ext_vector_type(8))) short;
typedef unsigned short u16;
typedef unsigned int u32;
typedef unsigned long long u64;

#define MFMA16(a,b,c) __builtin_amdgcn_mfma_f32_16x16x32_bf16(a,b,c,0,0,0)
#define SCOPE_A __HIP_MEMORY_SCOPE_AGENT
#define FP 16   // flag padding (ints) = 64B/flag
#define VNS 25

__device__ __forceinline__ float bf2f(u16 u){
  union { u32 i; float f; } v; v.i = ((u32)u) << 16; return v.f;
}
__device__ __forceinline__ u16 f2bf(float f){
  union { float f; u32 i; } v; v.f = f;
  u32 x = v.i;
  return (u16)((x + 0x7fffu + ((x >> 16) & 1u)) >> 16);
}
__device__ __forceinline__ float sigm(float x){ return 1.0f/(1.0f + expf(-x)); }

__device__ __forceinline__ s16x8 pack8(const float* p){
  s16x8 r;
  #pragma unroll
  for (int i = 0; i < 8; ++i) r[i] = (short)f2bf(p[i]);
  return r;
}

__device__ __forceinline__ void coh_st32(void* p, u32 v){
  __hip_atomic_store((u32*)p, v, __ATOMIC_RELAXED, SCOPE_A);
}
__device__ __forceinline__ float u2f(u32 u){ union { u32 i; float f; } v; v.i = u; return v.f; }
__device__ __forceinline__ u32 f2u(float f){ union { float f; u32 i; } v; v.f = f; return v.i; }

// flag sync: padded per-block flags (parallel stores, one line per flag)
__device__ __forceinline__ void poll(const int* flags, int n, int gen){
  for (int i = threadIdx.x; i < n; i += 256)
    while (__hip_atomic_load(flags + i*FP, __ATOMIC_RELAXED, SCOPE_A) < gen)
      __builtin_amdgcn_s_sleep(1);
  __syncthreads();
}
__device__ __forceinline__ void setflag(int* flag, int gen){
  __syncthreads();
  if (threadIdx.x == 0)
    __hip_atomic_store(flag, gen, __ATOMIC_RELAXED, SCOPE_A);
}

// K=1024 GEMM inner: plain cached A loads (16-deep staged) x 2 LDS B cols
__device__ __forceinline__ void gemm_k1024(
    const u16* ap, const char* wb0, const char* wb1, int xo, int addb,
    f32x4& a0, f32x4& a1)
{
  #pragma unroll
  for (int c = 0; c < 2; ++c){
    s16x8 st[16];
    #pragma unroll
    for (int q = 0; q < 16; ++q) st[q] = *(const s16x8*)(ap + c*512 + q*32);
    #pragma unroll
    for (int q = 0; q < 16; ++q){
      int cb = (addb + (c*512 + q*32)*2) ^ xo;
      a0 = MFMA16(st[q], *(const s16x8*)(wb0 + cb), a0);
      a1 = MFMA16(st[q], *(const s16x8*)(wb1 + cb), a1);
    }
  }
}

// ---------------- small utility kernels ----------------
__global__ void k_zero(float* __restrict__ p, long n){
  long i = (long)blockIdx.x*blockDim.x + threadIdx.x;
  long st = (long)gridDim.x*blockDim.x;
  for (; i < n; i += st) p[i] = 0.0f;
}

__device__ __forceinline__ void cast4(const float* s, u16* d){
  float4 v = *(const float4*)s;
  *(ushort4*)d = make_ushort4(f2bf(v.x), f2bf(v.y), f2bf(v.z), f2bf(v.w));
}

// fused prologue prep: all weight casts/repacks, bias adds, embedding gathers
__global__ void k_prep(
    const float* __restrict__ eWih_f, u16* __restrict__ Wih_f_bf,
    const float* __restrict__ eWih_b, u16* __restrict__ Wih_b_bf,
    const float* __restrict__ Wh, u16* __restrict__ Wh_bf,
    const float* __restrict__ Wc, u16* __restrict__ Wc_bf,
    const float* __restrict__ Watt, u16* __restrict__ Watt_bf,
    const float* __restrict__ Wcomb, u16* __restrict__ Wca_bf, u16* __restrict__ Whp_bf,
    const float* __restrict__ cnn_w, u16* __restrict__ Wconv_bf,
    const float* __restrict__ dWih, u16* __restrict__ Wy_bf,
    const float* __restrict__ ebih_f, const float* __restrict__ ebhh_f, float* __restrict__ benc_f,
    const float* __restrict__ ebih_b, const float* __restrict__ ebhh_b, float* __restrict__ benc_b,
    const float* __restrict__ dbih, const float* __restrict__ dbhh, float* __restrict__ bdec,
    const int* __restrict__ src_ids, const float* __restrict__ src_emb, u16* __restrict__ Aconv,
    const int* __restrict__ tgt_ids, const float* __restrict__ tgt_emb, u16* __restrict__ Ybf)
{
  const long N0 = 524288, N1 = 524288, N2 = 524288, N3 = 524288, N4 = 524288;
  const long N5 = 524288, N6 = 262144, N7 = 262144, N8 = 524288, N9 = 12288;
  const long N10 = 401408, N11 = 385024;
  const long total = N0+N1+N2+N3+N4+N5+N6+N7+N8+N9+N10+N11;
  for (long u = (long)blockIdx.x*256 + threadIdx.x; u < total; u += (long)gridDim.x*256){
    long x = u;
    if (x < N0){ cast4(eWih_f + x*4, Wih_f_bf + x*4); continue; } x -= N0;
    if (x < N1){ cast4(eWih_b + x*4, Wih_b_bf + x*4); continue; } x -= N1;
    if (x < N2){ cast4(Wh + x*4, Wh_bf + x*4); continue; } x -= N2;
    if (x < N3){ cast4(Wc + x*4, Wc_bf + x*4); continue; } x -= N3;
    if (x < N4){ cast4(Watt + x*4, Watt_bf + x*4); continue; } x -= N4;
    if (x < N5){ long r = x >> 9, c4 = x & 511;
      cast4(Wcomb + r*3072 + c4*4, Wca_bf + r*2048 + c4*4); continue; } x -= N5;
    if (x < N6){ long r = x >> 8, c4 = x & 255;
      cast4(Wcomb + r*3072 + 2048 + c4*4, Whp_bf + r*1024 + c4*4); continue; } x -= N6;
    if (x < N7){ long o = x >> 9, ii = x & 511;
      Wconv_bf[o*1024 + ii]       = f2bf(cnn_w[(o*512 + ii)*2 + 0]);
      Wconv_bf[o*1024 + 512 + ii] = f2bf(cnn_w[(o*512 + ii)*2 + 1]); continue; } x -= N7;
    if (x < N8){ long r = x >> 7, c4 = x & 127;
      cast4(dWih + r*1536 + 1024 + c4*4, Wy_bf + r*512 + c4*4); continue; } x -= N8;
    if (x < N9){ long k = x >> 12, j = x & 4095;
      if (k == 0) benc_f[j] = ebih_f[j] + ebhh_f[j];
      else if (k == 1) benc_b[j] = ebih_b[j] + ebhh_b[j];
      else bdec[j] = dbih[j] + dbhh[j];
      continue; } x -= N9;
    if (x < N10){ long s = x/8192, rem = x - s*8192, b = rem >> 7, e4 = rem & 127;
      float4 v = make_float4(0.f,0.f,0.f,0.f);
      if (s < 48){ int id = src_ids[s*64 + b]; v = *(const float4*)(src_emb + (size_t)id*512 + e4*4); }
      ushort4 uu = make_ushort4(f2bf(v.x), f2bf(v.y), f2bf(v.z), f2bf(v.w));
      if (s < 48) *(ushort4*)(Aconv + ((s*64 + b))*1024 + e4*4) = uu;
      if (s >= 1) *(ushort4*)(Aconv + (((s-1)*64 + b))*1024 + 512 + e4*4) = uu;
      continue; } x -= N10;
    { long tt = x/8192, rem = x - tt*8192, b = rem >> 7, e4 = rem & 127;
      int id = tgt_ids[tt*64 + b];
      cast4(tgt_emb + (size_t)id*512 + e4*4, Ybf + ((tt*64 + b))*512 + e4*4); }
  }
}

// ---------------- universal MFMA GEMM (prologue use) ----------------
// PACKG: gate-packed GP[time][j(1024)][gate(4)][b(64)] bf16
template<bool OUT_BF16, bool PACKG>
__global__ __launch_bounds__(256) void k_gemm(
    const u16* __restrict__ A0, long lda0,
    const u16* __restrict__ A1, long lda1, int ksplit,
    const u16* __restrict__ W, int K,
    void* __restrict__ Out, long ldc,
    const float* __restrict__ bias)
{
  __shared__ __align__(16) u16 As[64][72];
  __shared__ __align__(16) u16 Ws[64][72];
  const int t = threadIdx.x;
  const int m0 = blockIdx.x*64, n0 = blockIdx.y*64;
  const int w = t >> 6, l = t & 63, lr = l & 15, lh = l >> 4;
  const int sr = t >> 2, sk = (t & 3) << 4;

  f32x4 acc[4] = {{0,0,0,0},{0,0,0,0},{0,0,0,0},{0,0,0,0}};

  for (int kc = 0; kc < K; kc += 64){
    {
      const u16* wp = W + (size_t)(n0 + sr)*K + kc + sk;
      *(s16x8*)&Ws[sr][sk]     = *(const s16x8*)wp;
      *(s16x8*)&Ws[sr][sk + 8] = *(const s16x8*)(wp + 8);
    }
    {
      const u16* ap = (kc < ksplit)
        ? A0 + (size_t)(m0 + sr)*lda0 + kc
        : A1 + (size_t)(m0 + sr)*lda1 + (kc - ksplit);
      ap += sk;
      *(s16x8*)&As[sr][sk]     = *(const s16x8*)ap;
      *(s16x8*)&As[sr][sk + 8] = *(const s16x8*)(ap + 8);
    }
    __syncthreads();
    #pragma unroll
    for (int kk = 0; kk < 64; kk += 32){
      s16x8 a = *(const s16x8*)&As[w*16 + lr][kk + lh*8];
      #pragma unroll
      for (int ct = 0; ct < 4; ++ct){
        s16x8 bfr = *(const s16x8*)&Ws[ct*16 + lr][kk + lh*8];
        acc[ct] = MFMA16(a, bfr, acc[ct]);
      }
    }
    __syncthreads();
  }
  #pragma unroll
  for (int ct = 0; ct < 4; ++ct){
    #pragma unroll
    for (int rr = 0; rr < 4; ++rr){
      long row = m0 + w*16 + lh*4 + rr;
      long col = n0 + ct*16 + lr;
      float v = acc[ct][rr];
      if (bias) v += bias[col];
      if (PACKG){
        long time = row >> 6, b = row & 63, g = col >> 10, j = col & 1023;
        ((u16*)Out)[((time*1024 + j)*4 + g)*64 + b] = f2bf(v);
      } else {
        long oi = row*ldc + col;
        if (OUT_BF16) ((u16*)Out)[oi] = f2bf(v);
        else          ((float*)Out)[oi] = v;
      }
    }
  }
}

// fused encP/encWc GEMM: z=0 -> encP (Watt), z=1 -> encWc (Wca). A = Aatt, K=2048.
__global__ __launch_bounds__(256) void k_gemm_enc2(
    const u16* __restrict__ A, const u16* __restrict__ W0, const u16* __restrict__ W1,
    u16* __restrict__ O0, u16* __restrict__ O1)
{
  __shared__ __align__(16) u16 As[64][72];
  __shared__ __align__(16) u16 Ws[64][72];
  const int t = threadIdx.x;
  const int m0 = blockIdx.x*64, n0 = blockIdx.y*64;
  const u16* W = blockIdx.z ? W1 : W0;
  u16* Out = blockIdx.z ? O1 : O0;
  const int w = t >> 6, l = t & 63, lr = l & 15, lh = l >> 4;
  const int sr = t >> 2, sk = (t & 3) << 4;

  f32x4 acc[4] = {{0,0,0,0},{0,0,0,0},{0,0,0,0},{0,0,0,0}};
  for (int kc = 0; kc < 2048; kc += 64){
    {
      const u16* wp = W + (size_t)(n0 + sr)*2048 + kc + sk;
      *(s16x8*)&Ws[sr][sk]     = *(const s16x8*)wp;
      *(s16x8*)&Ws[sr][sk + 8] = *(const s16x8*)(wp + 8);
    }
    {
      const u16* ap = A + (size_t)(m0 + sr)*2048 + kc + sk;
      *(s16x8*)&As[sr][sk]     = *(const s16x8*)ap;
      *(s16x8*)&As[sr][sk + 8] = *(const s16x8*)(ap + 8);
    }
    __syncthreads();
    #pragma unroll
    for (int kk = 0; kk < 64; kk += 32){
      s16x8 a = *(const s16x8*)&As[w*16 + lr][kk + lh*8];
      #pragma unroll
      for (int ct = 0; ct < 4; ++ct){
        s16x8 bfr = *(const s16x8*)&Ws[ct*16 + lr][kk + lh*8];
        acc[ct] = MFMA16(a, bfr, acc[ct]);
      }
    }
    __syncthreads();
  }
  #pragma unroll
  for (int ct = 0; ct < 4; ++ct){
    #pragma unroll
    for (int rr = 0; rr < 4; ++rr){
      long row = m0 + w*16 + lh*4 + rr;
      long col = n0 + ct*16 + lr;
      Out[row*1024 + col] = f2bf(acc[ct][rr]);
    }
  }
}

// ---------------- persistent encoder + fused helpers ----------------
__global__ __launch_bounds__(256) void k_enc_persist(
    const float* __restrict__ WhhF, const float* __restrict__ WhhB,
    const u16* __restrict__ GfP, const u16* __restrict__ GbP,
    u16* __restrict__ hEF, u16* __restrict__ hEB,
    const u16* __restrict__ hzero,
    float* __restrict__ cF, float* __restrict__ cB,
    u16* __restrict__ Aatt, u16* __restrict__ cfbf, u16* __restrict__ cbbf,
    int* Eflags,
    const u16* __restrict__ Ybf, const u16* __restrict__ WyBf,
    const float* __restrict__ bdec, u16* __restrict__ GyP,
    const float* __restrict__ Wv, u16* __restrict__ WvBf)
{
  extern __shared__ char smem[];
  const int t = threadIdx.x, blk = blockIdx.x;
  const int w = t >> 6, l = t & 63, lr = l & 15, lh = l >> 4;

  if (blk >= 128){
    // ================= helpers: Gy pack GEMM + Wv cast =================
    const int hb = blk - 128;
    u16 (*As)[72] = (u16(*)[72])smem;
    u16 (*Ws)[72] = (u16(*)[72])(smem + 64*72*2);
    const int sr = t >> 2, sk = (t & 3) << 4;
    for (int tile = hb; tile < 47*64; tile += 128){
      int m0 = (tile % 47)*64, n0 = (tile / 47)*64;
      f32x4 acc[4] = {{0,0,0,0},{0,0,0,0},{0,0,0,0},{0,0,0,0}};
      for (int kc = 0; kc < 512; kc += 64){
        const u16* wp = WyBf + (size_t)(n0 + sr)*512 + kc + sk;
        *(s16x8*)&Ws[sr][sk]     = *(const s16x8*)wp;
        *(s16x8*)&Ws[sr][sk + 8] = *(const s16x8*)(wp + 8);
        const u16* ap = Ybf + (size_t)(m0 + sr)*512 + kc + sk;
        *(s16x8*)&As[sr][sk]     = *(const s16x8*)ap;
        *(s16x8*)&As[sr][sk + 8] = *(const s16x8*)(ap + 8);
        __syncthreads();
        #pragma unroll
        for (int kk = 0; kk < 64; kk += 32){
          s16x8 a = *(const s16x8*)&As[w*16 + lr][kk + lh*8];
          #pragma unroll
          for (int ct = 0; ct < 4; ++ct){
            s16x8 bfr = *(const s16x8*)&Ws[ct*16 + lr][kk + lh*8];
            acc[ct] = MFMA16(a, bfr, acc[ct]);
          }
        }
        __syncthreads();
      }
      #pragma unroll
      for (int ct = 0; ct < 4; ++ct){
        #pragma unroll
        for (int rr = 0; rr < 4; ++rr){
          long row = m0 + w*16 + lh*4 + rr;
          long col = n0 + ct*16 + lr;
          float v = acc[ct][rr] + bdec[col];
          long time = row >> 6, b = row & 63, g = col >> 10, j = col & 1023;
          GyP[((time*1024 + j)*4 + g)*64 + b] = f2bf(v);
        }
      }
    }
    for (long i = ((long)hb*256 + t)*4; i < (long)32000*1024; i += (long)128*256*4){
      float4 v = *(const float4*)(Wv + i);
      *(ushort4*)(WvBf + i) = make_ushort4(f2bf(v.x), f2bf(v.y), f2bf(v.z), f2bf(v.w));
    }
    return;
  }

  // ================= encoder =================
  const int dir = blk >> 6;
  const int j0 = (blk & 63) << 4;
  const float* Wsrc = dir ? WhhB : WhhF;
  const u16* GP = dir ? GbP : GfP;
  float* c = dir ? cB : cF;
  u16* cobf = dir ? cbbf : cfbf;
  u16* hE = dir ? hEB : hEF;
  int* myflags = Eflags + dir*64*FP;
  const int myidx = blk & 63;

  for (int q = t; q < 64*128; q += 256){
    int row = q >> 7;
    int ck = (q & 127) << 3;
    int wrow = ((row >> 4)*1024) + j0 + (row & 15);
    s16x8 pk = pack8(Wsrc + (size_t)wrow*1024 + ck);
    *(s16x8*)(smem + row*2048 + ((ck*2) ^ ((row & 7) << 4))) = pk;
  }
  __syncthreads();

  const int lane_m = w*16 + lr;
  const int koff = lh*8;
  const char* wp0 = smem + lr*2048;
  const char* wp1 = smem + (16 + lr)*2048;
  const char* wp2 = smem + (32 + lr)*2048;
  const char* wp3 = smem + (48 + lr)*2048;
  const int xo = (lr & 7) << 4;
  const int j = j0 + lr;

  for (int s = 0; s < 48; ++s){
    const u16* hin = s ? (hE + (size_t)(s - 1)*65536) : hzero;
    u16* hout      = hE + (size_t)s*65536;
    const int time = dir ? 47 - s : s;
    if (s) poll(myflags, 64, s);
    f32x4 a0 = {0,0,0,0}, a1 = {0,0,0,0}, a2 = {0,0,0,0}, a3 = {0,0,0,0};
    const u16* ap = hin + (size_t)lane_m*1024 + koff;
    #pragma unroll
    for (int cc = 0; cc < 2; ++cc){
      s16x8 st[16];
      #pragma unroll
      for (int q = 0; q < 16; ++q) st[q] = *(const s16x8*)(ap + cc*512 + q*32);
      #pragma unroll
      for (int q = 0; q < 16; ++q){
        int cb = ((cc*512 + q*32 + koff)*2) ^ xo;
        a0 = MFMA16(st[q], *(const s16x8*)(wp0 + cb), a0);
        a1 = MFMA16(st[q], *(const s16x8*)(wp1 + cb), a1);
        a2 = MFMA16(st[q], *(const s16x8*)(wp2 + cb), a2);
        a3 = MFMA16(st[q], *(const s16x8*)(wp3 + cb), a3);
      }
    }
    #pragma unroll
    for (int rr = 0; rr < 4; ++rr){
      int b = w*16 + lh*4 + rr;
      const u16* gp = GP + (((size_t)time*1024 + j)*4)*64 + b;
      float gi = a0[rr] + bf2f(gp[0]);
      float gf = a1[rr] + bf2f(gp[64]);
      float gg = a2[rr] + bf2f(gp[128]);
      float go = a3[rr] + bf2f(gp[192]);
      float cn = sigm(gf)*c[b*1024 + j] + sigm(gi)*tanhf(gg);
      float hn = sigm(go)*tanhf(cn);
      c[b*1024 + j] = cn;
      u16 hb = f2bf(hn);
      u32 hi2 = __shfl_down((u32)hb, 1);
      if ((lr & 1) == 0)
        coh_st32((u32*)hout + ((b*1024 + j) >> 1), (u32)hb | (hi2 << 16));
      Aatt[((size_t)b*48 + time)*2048 + dir*1024 + j] = hb;
      if (s == 47) cobf[b*1024 + j] = f2bf(cn);
    }
    setflag(myflags + myidx*FP, s + 1);
  }
}

// ---------------- persistent decoder (r12-proven structure) ----------------
__global__ __launch_bounds__(256) void k_dec_persist(
    const float* __restrict__ dWih, const float* __restrict__ dWhh,
    const u16* __restrict__ GyP,
    const u16* __restrict__ encP, const u16* __restrict__ encWc,
    const u16* __restrict__ Whp,
    const u16* __restrict__ hbinit, u16* __restrict__ hD,
    float* __restrict__ cdec,
    u16* __restrict__ hp, u16* __restrict__ Cbf,
    const u16* __restrict__ obf_zero,
    int* Gflags, int* G2flags, int* Cflags)
{
  extern __shared__ char smem[];
  const int t = threadIdx.x, blk = blockIdx.x;
  const int w = t >> 6, l = t & 63, lr = l & 15, lh = l >> 4;
  const int lane_m = w*16 + lr;
  const int koff = lh*8;
  const int xo = (lr & 7) << 4;

  if (blk < 128){
    // ================= G: gates GEMM + LSTM + hpart =================
    const int j0 = blk << 3;
    for (int q = t; q < 32*256; q += 256){
      int row = q >> 8;
      int ck = (q & 255) << 3;
      int wrow = ((row >> 3)*1024) + j0 + (row & 7);
      const float* src = (ck < 1024) ? dWih + (size_t)wrow*1536 + ck
                                     : dWhh + (size_t)wrow*1024 + (ck - 1024);
      s16x8 pk = pack8(src);
      *(s16x8*)(smem + row*4096 + ((ck*2) ^ ((row & 7) << 4))) = pk;
    }
    char* WhpL = smem + 131072;
    for (int q = t; q < 8*128; q += 256){
      int row = q >> 7, ck = (q & 127) << 3;
      s16x8 v = *(const s16x8*)(Whp + (size_t)(j0 + row)*1024 + ck);
      *(s16x8*)(WhpL + row*2048 + ((ck*2) ^ ((row & 7) << 4))) = v;
    }
    __syncthreads();
    const char* wp0 = smem + lr*4096;
    const char* wp1 = smem + (16 + lr)*4096;
    const char* wph = WhpL + (lr & 7)*2048;
    const int jj = lr & 7, gsel = lr >> 3;
    const int j = j0 + jj;

    s16x8 hreg[32];
    {
      const u16* ap = hbinit + (size_t)lane_m*1024 + koff;
      #pragma unroll
      for (int q = 0; q < 32; ++q) hreg[q] = *(const s16x8*)(ap + q*32);
    }

    for (int tt = 0; tt < 47; ++tt){
      u16* hout = hD + (size_t)tt*65536;
      f32x4 a0 = {0,0,0,0}, a1 = {0,0,0,0};
      #pragma unroll
      for (int q = 0; q < 32; ++q){
        int cb = ((1024 + q*32 + koff)*2) ^ xo;
        a0 = MFMA16(hreg[q], *(const s16x8*)(wp0 + cb), a0);
        a1 = MFMA16(hreg[q], *(const s16x8*)(wp1 + cb), a1);
      }
      if (tt) poll(Cflags, 64, tt);           // Cbf[tt-1] ready
      const u16* Ao = tt ? (Cbf + (size_t)(tt - 1)*65536) : obf_zero;
      gemm_k1024(Ao + (size_t)lane_m*1024 + koff, wp0, wp1, xo, koff*2, a0, a1);
      #pragma unroll
      for (int rr = 0; rr < 4; ++rr){
        float v0 = a0[rr], v1 = a1[rr];
        float p0 = __shfl_xor(v0, 8, 64);
        float p1 = __shfl_xor(v1, 8, 64);
        if (gsel == 0){
          int b = w*16 + lh*4 + rr;
          const u16* gp = GyP + (((size_t)tt*1024 + j)*4)*64 + b;
          float gi = v0 + bf2f(gp[0]);
          float gf = p0 + bf2f(gp[64]);
          float gg = v1 + bf2f(gp[128]);
          float go = p1 + bf2f(gp[192]);
          float cn = sigm(gf)*cdec[b*1024 + j] + sigm(gi)*tanhf(gg);
          float hn = sigm(go)*tanhf(cn);
          cdec[b*1024 + j] = cn;
          u16 hb = f2bf(hn);
          u32 hi2 = __shfl_down((u32)hb, 1);
          if ((jj & 1) == 0)
            coh_st32((u32*)hout + ((b*1024 + j) >> 1), (u32)hb | (hi2 << 16));
        }
      }
      setflag(Gflags + blk*FP, tt + 1);
      poll(Gflags, 128, tt + 1);              // full h[tt] ready (peers)
      {
        const u16* ap = hout + (size_t)lane_m*1024 + koff;
        #pragma unroll
        for (int q = 0; q < 32; ++q) hreg[q] = *(const s16x8*)(ap + q*32);
      }
      // hpart (bf16) for own 8 cols: h[tt] @ Whp_slice^T
      f32x4 hpacc = {0,0,0,0};
      #pragma unroll
      for (int q = 0; q < 32; ++q){
        int cb = ((q*32 + koff)*2) ^ xo;
        s16x8 bw = {0,0,0,0,0,0,0,0};
        if (lr < 8) bw = *(const s16x8*)(wph + cb);
        hpacc = MFMA16(hreg[q], bw, hpacc);
      }
      if (lr < 8){
        u16* hpout = hp + (size_t)tt*65536;
        #pragma unroll
        for (int rr = 0; rr < 4; ++rr){
          u16 hb = f2bf(hpacc[rr]);
          u32 hi2 = __shfl_down((u32)hb, 1);
          if ((lr & 1) == 0)
            coh_st32((u32*)hpout + (((size_t)(w*16 + lh*4 + rr)*1024 + j0 + lr) >> 1),
                     (u32)hb | (hi2 << 16));
        }
      }
      setflag(G2flags + blk*FP, tt + 1);
    }
  } else {
    // ================= SC: scores + softmax + PV + combine (batch b) =========
    const int b = blk - 128;
    u16* encPL = (u16*)smem;              // [48][1024] bf16
    float* hs  = (float*)(smem + 98304);  // [1024]
    float* es  = (float*)(smem + 102400); // [48]
    float* al  = es + 48;                 // [48]
    for (int q = t; q < 48*128; q += 256){
      int row = q >> 7, ck = (q & 127) << 3;
      *(s16x8*)&encPL[row*1024 + ck] =
        *(const s16x8*)(encP + ((size_t)b*48 + row)*1024 + ck);
    }
    __syncthreads();

    for (int tt = 0; tt < 47; ++tt){
      poll(Gflags, 128, tt + 1);           // h[tt] ready
      const u16* hrow = hD + (size_t)tt*65536 + (size_t)b*1024;
      {
        ushort4 v4 = ((const ushort4*)hrow)[t];
        hs[4*t]     = bf2f(v4.x);
        hs[4*t + 1] = bf2f(v4.y);
        hs[4*t + 2] = bf2f(v4.z);
        hs[4*t + 3] = bf2f(v4.w);
      }
      __syncthreads();
      for (int s2 = w; s2 < 48; s2 += 4){
        float p = 0.f;
        #pragma unroll
        for (int i = 0; i < 16; ++i)
          p += hs[l + 64*i]*bf2f(encPL[s2*1024 + l + 64*i]);
        #pragma unroll
        for (int d = 32; d >= 1; d >>= 1) p += __shfl_xor(p, d, 64);
        if (l == 0) es[s2] = p;
      }
      __syncthreads();
      if (w == 0){
        float e = (l < 48) ? es[l] : -INFINITY;
        float m = e;
        #pragma unroll
        for (int d = 32; d >= 1; d >>= 1) m = fmaxf(m, __shfl_xor(m, d, 64));
        float ex = (l < 48) ? expf(e - m) : 0.f;
        float su = ex;
        #pragma unroll
        for (int d = 32; d >= 1; d >>= 1) su += __shfl_xor(su, d, 64);
        if (l < 48) al[l] = ex/su;
      }
      __syncthreads();
      poll(G2flags, 128, tt + 1);          // hpart[tt] ready
      int c0 = t*4;
      ushort4 h4 = *(const ushort4*)(hp + (size_t)tt*65536 + (size_t)b*1024 + c0);
      float acc0 = 0.f, acc1 = 0.f, acc2 = 0.f, acc3 = 0.f;
      const u16* ew = encWc + (size_t)b*48*1024 + c0;
      #pragma unroll 4
      for (int s2 = 0; s2 < 48; ++s2){
        float wgt = al[s2];
        ushort4 e4 = *(const ushort4*)(ew + (size_t)s2*1024);
        acc0 += wgt*bf2f(e4.x); acc1 += wgt*bf2f(e4.y);
        acc2 += wgt*bf2f(e4.z); acc3 += wgt*bf2f(e4.w);
      }
      float v0 = tanhf(bf2f(h4.x) + acc0), v1 = tanhf(bf2f(h4.y) + acc1);
      float v2 = tanhf(bf2f(h4.z) + acc2), v3 = tanhf(bf2f(h4.w) + acc3);
      size_t oi = (size_t)tt*65536 + (size_t)b*1024 + c0;
      coh_st32((u32*)Cbf + (oi >> 1),     (u32)f2bf(v0) | ((u32)f2bf(v1) << 16));
      coh_st32((u32*)Cbf + (oi >> 1) + 1, (u32)f2bf(v2) | ((u32)f2bf(v3) << 16));
      setflag(Cflags + b*FP, tt + 1);
    }
  }
}

// ---------------- fused vocab GEMM + online logsumexp ----------------
__global__ __launch_bounds__(256) void k_vocab_lse(
    const u16* __restrict__ Cbf, const u16* __restrict__ Wv, float2* __restrict__ partials)
{
  __shared__ __align__(16) u16 As[128][72];
  __shared__ __align__(16) u16 Bs[128][72];
  __shared__ float2 mg[128][2];
  int rb = blockIdx.x, sp = blockIdx.y;
  int m0 = rb*128;
  int t = threadIdx.x, w = t >> 6, l = t & 63, lr = l & 15, lh = l >> 4;
  int wr = w >> 1, wc = w & 1;
  int sr = t >> 1, sk = (t & 1) << 5;

  float mrun[4][4], srun[4][4];
  #pragma unroll
  for (int m = 0; m < 4; ++m)
    #pragma unroll
    for (int rr = 0; rr < 4; ++rr){ mrun[m][rr] = -INFINITY; srun[m][rr] = 0.f; }

  for (int nt = 0; nt < 10; ++nt){
    int n0 = sp*1280 + nt*128;
    f32x4 acc[4][4];
    #pragma unroll
    for (int m = 0; m < 4; ++m)
      #pragma unroll
      for (int n = 0; n < 4; ++n) acc[m][n] = (f32x4){0,0,0,0};

    for (int kc = 0; kc < 1024; kc += 64){
      int ar = m0 + sr; if (ar > 3007) ar = 3007;
      const u16* ap = Cbf + (size_t)ar*1024 + kc + sk;
      const u16* wp = Wv + (size_t)(n0 + sr)*1024 + kc + sk;
      #pragma unroll
      for (int q = 0; q < 4; ++q){
        *(s16x8*)&As[sr][sk + q*8] = *(const s16x8*)(ap + q*8);
        *(s16x8*)&Bs[sr][sk + q*8] = *(const s16x8*)(wp + q*8);
      }
      __syncthreads();
      #pragma unroll
      for (int kk = 0; kk < 64; kk += 32){
        s16x8 af[4], bf[4];
        #pragma unroll
        for (int m = 0; m < 4; ++m)
          af[m] = *(const s16x8*)&As[wr*64 + m*16 + lr][kk + lh*8];
        #pragma unroll
        for (int n = 0; n < 4; ++n)
          bf[n] = *(const s16x8*)&Bs[wc*64 + n*16 + lr][kk + lh*8];
        #pragma unroll
        for (int m = 0; m < 4; ++m)
          #pragma unroll
          for (int n = 0; n < 4; ++n)
            acc[m][n] = MFMA16(af[m], bf[n], acc[m][n]);
      }
      __syncthreads();
    }
    #pragma unroll
    for (int m = 0; m < 4; ++m){
      #pragma unroll
      for (int rr = 0; rr < 4; ++rr){
        float tm = fmaxf(fmaxf(acc[m][0][rr], acc[m][1][rr]),
                         fmaxf(acc[m][2][rr], acc[m][3][rr]));
        #pragma unroll
        for (int d = 1; d < 16; d <<= 1) tm = fmaxf(tm, __shfl_xor(tm, d, 64));
        float ts = expf(acc[m][0][rr] - tm) + expf(acc[m][1][rr] - tm)
                 + expf(acc[m][2][rr] - tm) + expf(acc[m][3][rr] - tm);
        #pragma unroll
        for (int d = 1; d < 16; d <<= 1) ts += __shfl_xor(ts, d, 64);
        if (tm > mrun[m][rr]){ srun[m][rr] = srun[m][rr]*expf(mrun[m][rr] - tm) + ts; mrun[m][rr] = tm; }
        else srun[m][rr] += ts*expf(tm - mrun[m][rr]);
      }
    }
  }
  __syncthreads();
  if (lr == 0){
    #pragma unroll
    for (int m = 0; m < 4; ++m)
      #pragma unroll
      for (int rr = 0; rr < 4; ++rr)
        mg[wr*64 + m*16 + lh*4 + rr][wc] = make_float2(mrun[m][rr], srun[m][rr]);
  }
  __syncthreads();
  if (t < 128){
    float2 p0 = mg[t][0], p1 = mg[t][1];
    float m = fmaxf(p0.x, p1.x);
    float s = p0.y*expf(p0.x - m) + p1.y*expf(p1.x - m);
    long row = m0 + t;
    if (row < 3008) partials[row*VNS + sp] = make_float2(m, s);
  }
}

__global__ void k_lse(const float2* __restrict__ partials, float* __restrict__ lse){
  int r = blockIdx.x*256 + threadIdx.x;
  if (r >= 3008) return;
  float m = -INFINITY, s = 0.f;
  for (int i = 0; i < VNS; ++i){
    float2 p = partials[r*VNS + i];
    if (p.x > m){ s = s*expf(m - p.x) + p.y; m = p.x; }
    else s += p.y*expf(p.x - m);
  }
  lse[r] = m + logf(s);
}

__global__ __launch_bounds__(256) void k_gold(const u16* __restrict__ Cbf,
                                              const u16* __restrict__ Wv,
                                              const int* __restrict__ tgt,
                                              float* __restrict__ gold){
  int w = threadIdx.x >> 6, l = threadIdx.x & 63;
  int r = blockIdx.x*4 + w;
  int tt = r >> 6, b = r & 63;
  int gid = tgt[(tt + 1)*64 + b];
  const u16* cp = Cbf + (size_t)r*1024;
  const u16* wp = Wv + (size_t)gid*1024;
  float p = 0.f;
  for (int i = l; i < 1024; i += 64) p += bf2f(cp[i])*bf2f(wp[i]);
  for (int d = 32; d >= 1; d >>= 1) p += __shfl_xor(p, d, 64);
  if (l == 0) gold[r] = p;
}

__global__ void k_final(const float* __restrict__ gold, const float* __restrict__ lse,
                        const int* __restrict__ tgt, float* __restrict__ out){
  int b = threadIdx.x;
  if (b >= 64) return;
  float acc = 0.f;
  for (int t = 0; t < 47; ++t){
    int gid = tgt[(t + 1)*64 + b];
    if (gid != 0) acc += gold[t*64 + b] - lse[t*64 + b];
  }
  out[b] = acc;
}

// ---------------- host ----------------
extern "C" void kernel_launch(void* const* d_in, const int* in_sizes, int n_in,
                              void* d_out, int out_size, void* d_ws, size_t ws_size,
                              hipStream_t stream)
{
  (void)in_sizes; (void)n_in; (void)out_size; (void)ws_size;
  const int*   src_ids = (const int*)d_in[0];
  const int*   tgt_ids = (const int*)d_in[1];
  const float* src_emb = (const float*)d_in[3];
  const float* tgt_emb = (const float*)d_in[4];
  const float* cnn_w   = (const float*)d_in[5];
  const float* cnn_b   = (const float*)d_in[6];
  const float* eWih_f  = (const float*)d_in[7];
  const float* eWhh_f  = (const float*)d_in[8];
  const float* ebih_f  = (const float*)d_in[9];
  const float* ebhh_f  = (const float*)d_in[10];
  const float* eWih_b  = (const float*)d_in[11];
  const float* eWhh_b  = (const float*)d_in[12];
  const float* ebih_b  = (const float*)d_in[13];
  const float* ebhh_b  = (const float*)d_in[14];
  const float* dWih    = (const float*)d_in[15];
  const float* dWhh    = (const float*)d_in[16];
  const float* dbih    = (const float*)d_in[17];
  const float* dbhh    = (const float*)d_in[18];
  const float* Wh      = (const float*)d_in[19];
  const float* Wc      = (const float*)d_in[20];
  const float* Watt    = (const float*)d_in[21];
  const float* Wcomb   = (const float*)d_in[22];
  const float* Wvocab  = (const float*)d_in[23];

  char* ws = (char*)d_ws;
  size_t off = 0;
  auto alloc = [&](size_t bytes)->char*{
    char* p = ws + off;
    off = (off + bytes + 255) & ~(size_t)255;
    return p;
  };

  // --- zero region (contiguous, re-zeroed every launch) ---
  float* cF     = (float*)alloc((size_t)65536*4);
  float* cB     = (float*)alloc((size_t)65536*4);
  u16* obf_zero = (u16*)alloc((size_t)65536*2);
  int* bar      = (int*)alloc(32768);
  size_t zero_floats = ((size_t)262144*2 + 131072 + 32768)/4;
  int* Eflags  = bar;            // 128*FP ints
  int* Gflags  = bar + 2048;     // 128*FP
  int* G2flags = bar + 4096;     // 128*FP
  int* Cflags  = bar + 6144;     // 64*FP

  // --- weights (bf16) ---
  u16* Wconv_bf = (u16*)alloc((size_t)512*1024*2);
  u16* Wih_f_bf = (u16*)alloc((size_t)4096*512*2);
  u16* Wih_b_bf = (u16*)alloc((size_t)4096*512*2);
  u16* Wy_bf    = (u16*)alloc((size_t)4096*512*2);
  u16* Wh_bf    = (u16*)alloc((size_t)1024*2048*2);
  u16* Wc_bf    = (u16*)alloc((size_t)1024*2048*2);
  u16* Watt_bf  = (u16*)alloc((size_t)1024*2048*2);
  u16* Wca_bf   = (u16*)alloc((size_t)1024*2048*2);
  u16* Whp_bf   = (u16*)alloc((size_t)1024*1024*2);
  u16* Wv_bf    = (u16*)alloc((size_t)32000*1024*2);
  float* benc_f = (float*)alloc(4096*4);
  float* benc_b = (float*)alloc(4096*4);
  float* bdec   = (float*)alloc(4096*4);

  // --- activations ---
  u16* Aconv    = (u16*)alloc((size_t)3072*1024*2);
  u16* Xc       = (u16*)alloc((size_t)3072*512*2);
  u16* GfP      = (u16*)alloc((size_t)48*1024*256*2);
  u16* GbP      = (u16*)alloc((size_t)48*1024*256*2);
  u16* GyP      = (u16*)alloc((size_t)47*1024*256*2);
  u16* Ybf      = (u16*)alloc((size_t)3008*512*2);
  u16* Aatt     = (u16*)alloc((size_t)3072*2048*2);
  u16* encP     = (u16*)alloc((size_t)3072*1024*2);
  u16* encWc    = (u16*)alloc((size_t)3072*1024*2);
  u16* hEF      = (u16*)alloc((size_t)48*65536*2);
  u16* hEB      = (u16*)alloc((size_t)48*65536*2);
  u16* cfbf     = (u16*)alloc((size_t)65536*2);
  u16* cbbf     = (u16*)alloc((size_t)65536*2);
  u16* hbinit   = (u16*)alloc((size_t)65536*2);
  u16* hD       = (u16*)alloc((size_t)47*65536*2);
  float* cdec   = (float*)alloc((size_t)65536*4);
  u16* hp       = (u16*)alloc((size_t)47*65536*2);      // hpart ring (bf16)
  u16* Cbf      = (u16*)alloc((size_t)3008*1024*2);
  float2* partials=(float2*)alloc((size_t)3008*VNS*8);
  float* lse    = (float*)alloc(3008*4);
  float* gold   = (float*)alloc(3008*4);

  k_zero<<<256, 256, 0, stream>>>(cF, (long)zero_floats);

  // fused prologue prep (replaces 11 small launches)
  k_prep<<<1024, 256, 0, stream>>>(
      eWih_f, Wih_f_bf, eWih_b, Wih_b_bf, Wh, Wh_bf, Wc, Wc_bf, Watt, Watt_bf,
      Wcomb, Wca_bf, Whp_bf, cnn_w, Wconv_bf, dWih, Wy_bf,
      ebih_f, ebhh_f, benc_f, ebih_b, ebhh_b, benc_b, dbih, dbhh, bdec,
      src_ids, src_emb, Aconv, tgt_ids, tgt_emb, Ybf);

  // conv + encoder input-gate precomputes (gate-packed outputs)
  k_gemm<true, false><<<dim3(48, 8), 256, 0, stream>>>(
      Aconv, 1024, Aconv, 1024, 1024, Wconv_bf, 1024, Xc, 512, cnn_b);
  k_gemm<true, true><<<dim3(48, 64), 256, 0, stream>>>(
      Xc, 512, Xc, 512, 512, Wih_f_bf, 512, GfP, 0, benc_f);
  k_gemm<true, true><<<dim3(48, 64), 256, 0, stream>>>(
      Xc, 512, Xc, 512, 512, Wih_b_bf, 512, GbP, 0, benc_b);

  // persistent bidirectional encoder + fused helpers (Gy pack + Wv cast)
  k_enc_persist<<<256, 256, 131072, stream>>>(
      eWhh_f, eWhh_b, GfP, GbP, hEF, hEB, obf_zero, cF, cB,
      Aatt, cfbf, cbbf, Eflags,
      Ybf, Wy_bf, bdec, GyP, Wvocab, Wv_bf);

  // decoder init: dec_h (bf16), dec_c
  k_gemm<true, false><<<dim3(1, 16), 256, 0, stream>>>(
      hEF + (size_t)47*65536, 1024, hEB + (size_t)47*65536, 1024, 1024,
      Wh_bf, 2048, hbinit, 1024, nullptr);
  k_gemm<false, false><<<dim3(1, 16), 256, 0, stream>>>(
      cfbf, 1024, cbbf, 1024, 1024, Wc_bf, 2048, cdec, 1024, nullptr);
  // encP + encWc fused (z=0: Watt -> encP, z=1: Wca -> encWc)
  k_gemm_enc2<<<dim3(48, 16, 2), 256, 0, stream>>>(
      Aatt, Watt_bf, Wca_bf, encP, encWc);

  // persistent decoder (r12-proven G + SC, padded flag sync)
  k_dec_persist<<<192, 256, 147456, stream>>>(
      dWih, dWhh, GyP, encP, encWc, Whp_bf, hbinit, hD, cdec,
      hp, Cbf, obf_zero, Gflags, G2flags, Cflags);

  // vocab logsumexp + gold + final
  k_vocab_lse<<<dim3(24, VNS), 256, 0, stream>>>(Cbf, Wv_bf, partials);
  k_lse<<<12, 256, 0, stream>>>(partials, lse);
  k_gold<<<752, 256, 0, stream>>>(Cbf, Wv_bf, tgt_ids, gold);
  k_final<<<1, 64, 0, stream>>>(gold, lse, tgt_ids, (float*)d_out);
}